// Round 3
// baseline (1504.218 us; speedup 1.0000x reference)
//
#include <hip/hip_runtime.h>
#include <cmath>

namespace {
constexpr int kNZ = 300, kNX = 400;
constexpr int kNPML = 32;
constexpr int kNZP = 364, kNXP = 464;       // padded physical grid
constexpr int kNSTEPS = 200, kNSHOTS = 2;
constexpr int kSRC_Z = 34, kREC_Z = 34;     // NPML + 2
constexpr float kDT = 0.001f;
constexpr float kINV_DX = 100.0f;           // 1/DX
constexpr int kG = 4;                        // guard ring (zero pad) for cone reads
constexpr int kP = kNXP + 2 * kG;            // guarded pitch = 472
constexpr int kR = kNZP + 2 * kG;            // guarded rows = 372
constexpr int kNC = kP * kR;                 // guarded cells = 175584
constexpr int kNCELL = kNZP * kNXP;          // 168896
constexpr int kNTASK = kNSHOTS * kNCELL;     // 337792
constexpr int kPAIRS = kNSTEPS / 2;          // 100 fused 2-step dispatches

// L1-ball (diamond) offset tables for the 2-step dependency cone.
constexpr int D1z[5]  = {0,0,0,1,-1};
constexpr int D1x[5]  = {0,1,-1,0,0};
constexpr int D2z[13] = {-2,-1,-1,-1, 0, 0,0,0,0, 1,1,1, 2};
constexpr int D2x[13] = { 0,-1, 0, 1,-2,-1,0,1,2,-1,0,1, 0};
constexpr int D3z[25] = {-3,-2,-2,-2,-1,-1,-1,-1,-1, 0, 0, 0,0,0,0,0, 1, 1,1,1,1, 2,2,2, 3};
constexpr int D3x[25] = { 0,-1, 0, 1,-2,-1, 0, 1, 2,-3,-2,-1,0,1,2,3,-2,-1,0,1,2,-1,0,1, 0};

__host__ __device__ constexpr int id2(int dz, int dx) {  // index into D2 arrays
  const int S[5] = {0, 1, 4, 9, 12};
  const int a = dz < 0 ? -dz : dz;
  return S[dz + 2] + dx + (2 - a);
}
__host__ __device__ constexpr int id3(int dz, int dx) {  // index into D3 arrays
  const int S[7] = {0, 1, 4, 9, 16, 21, 24};
  const int a = dz < 0 ? -dz : dz;
  return S[dz + 3] + dx + (3 - a);
}
}  // namespace

// ws layout (floats):
//   vmod float2[kNC] = {dtr, damp}              (2*kNC)   zero in guard/out-of-grid
//   smod float4[kNC] = {lam', mu', lam2mu', damp} (4*kNC)
//   fields buf[2][shot][5][kNC]                 (20*kNC)  guard cells stay 0 forever
//   loss[1]
// All moduli premultiplied by DT/DX exactly as the round-2 kernel (bit-exact).

__global__ void fwi_init_kernel(const float* __restrict__ Vp,
                                const float* __restrict__ Vs,
                                const float* __restrict__ Den,
                                float* __restrict__ ws) {
    float2* vmod = (float2*)ws;
    float4* smod = (float4*)(ws + 2 * kNC);
    float*  fld  = ws + 6 * kNC;
    float*  lossp = ws + 26 * kNC;

    const int gtid = blockIdx.x * blockDim.x + threadIdx.x;
    const int gstride = gridDim.x * blockDim.x;
    for (int c2 = gtid; c2 < kNC; c2 += gstride) {
        const int r = c2 / kP;
        const int q = c2 - r * kP;
        const int i = r - kG;
        const int j = q - kG;
        float2 vm = make_float2(0.0f, 0.0f);
        float4 sm = make_float4(0.0f, 0.0f, 0.0f, 0.0f);
        if (i >= 0 && i < kNZP && j >= 0 && j < kNXP) {
            int iz = i - kNPML; iz = iz < 0 ? 0 : (iz > kNZ - 1 ? kNZ - 1 : iz);
            int jx = j - kNPML; jx = jx < 0 ? 0 : (jx > kNX - 1 ? kNX - 1 : jx);
            const float vp  = Vp[iz * kNX + jx];
            const float vs  = Vs[iz * kNX + jx];
            const float rho = Den[iz * kNX + jx];
            const float m = vs * vs * rho * 1e-6f;
            const float l = (vp * vp - 2.0f * vs * vs) * rho * 1e-6f;
            const float sc = kDT * kINV_DX;
            float dz = fmaxf((float)(kNPML - i), (float)(i - (kNZP - 1 - kNPML)));
            dz = fminf(fmaxf(dz, 0.0f), (float)kNPML) * (1.0f / kNPML);
            float dxx = fmaxf((float)(kNPML - j), (float)(j - (kNXP - 1 - kNPML)));
            dxx = fminf(fmaxf(dxx, 0.0f), (float)kNPML) * (1.0f / kNPML);
            const float damp = expf(-0.1f * (dz * dz + dxx * dxx));
            vm = make_float2(kDT / rho * kINV_DX, damp);
            sm = make_float4(l * sc, m * sc, (l + 2.0f * m) * sc, damp);
        }
        vmod[c2] = vm;
        smod[c2] = sm;
    }
    for (int c = gtid; c < 20 * kNC; c += gstride) fld[c] = 0.0f;
    if (gtid == 0) lossp[0] = 0.0f;
}

// Two full timesteps fused per dispatch via branchless dependency-cone
// recompute (guard ring makes every read in-bounds; damp=0 outside the grid
// forces out-of-grid intermediates to the reference's zero padding).
__global__ __launch_bounds__(256, 2) void fwi_step2_kernel(
    float* __restrict__ ws, const float* __restrict__ Stf,
    const int* __restrict__ Shot_ids, int pair) {
    const int task = blockIdx.x * blockDim.x + threadIdx.x;

    const float2* __restrict__ vmod = (const float2*)ws;
    const float4* __restrict__ smod = (const float4*)(ws + 2 * kNC);
    float* fld   = ws + 6 * kNC;
    float* lossp = ws + 26 * kNC;

    float rsum = 0.0f;
    if (task < kNTASK) {
        const int s = (task >= kNCELL) ? 1 : 0;
        const int c = task - s * kNCELL;
        const int i = c / kNXP;
        const int j = c - i * kNXP;
        const int c2 = (i + kG) * kP + (j + kG);

        const int p = pair & 1;
        const float* Fc = fld + (p * kNSHOTS + s) * 5 * kNC;
        float*       Fn = fld + ((1 - p) * kNSHOTS + s) * 5 * kNC;
        const float* __restrict__ vx0  = Fc;
        const float* __restrict__ vz0  = Fc + kNC;
        const float* __restrict__ sxx0 = Fc + 2 * kNC;
        const float* __restrict__ szz0 = Fc + 3 * kNC;
        const float* __restrict__ sxz0 = Fc + 4 * kNC;

        const int id  = Shot_ids[s];
        const int sxp = kNPML + 20 + id * ((kNX - 40) / kNSHOTS);
        const int tt  = 2 * pair;
        const float svalA = Stf[id * kNSTEPS + tt] * kDT;
        const float svalB = Stf[id * kNSTEPS + tt + 1] * kDT;
        const int di = kSRC_Z - i;   // source offset relative to this thread
        const int dj = sxp - j;

        // ---- phase 1: step-A velocities on diamond r<=3 (25 cells) ----
        float vxA[25], vzA[25];
#pragma unroll
        for (int k = 0; k < 25; ++k) {
            const int cc = c2 + D3z[k] * kP + D3x[k];
            const float2 dd = vmod[cc];
            vxA[k] = (vx0[cc] + dd.x * ((sxx0[cc + 1] - sxx0[cc]) + (sxz0[cc] - sxz0[cc - kP]))) * dd.y;
            vzA[k] = (vz0[cc] + dd.x * ((sxz0[cc] - sxz0[cc - 1]) + (szz0[cc + kP] - szz0[cc]))) * dd.y;
        }
        // ---- phase 2: step-A stresses on diamond r<=2 (13 cells) ----
        float sxxA[13], szzA[13], sxzA[13];
#pragma unroll
        for (int k = 0; k < 13; ++k) {
            const int dz = D2z[k], dx = D2x[k];
            const int cc = c2 + dz * kP + dx;
            const float4 sm = smod[cc];
            const float vxc = vxA[id3(dz, dx)];
            const float vzc = vzA[id3(dz, dx)];
            const float dvx = vxc - vxA[id3(dz, dx - 1)];
            const float dvz = vzc - vzA[id3(dz - 1, dx)];
            float nsxx = (sxx0[cc] + (sm.z * dvx + sm.x * dvz)) * sm.w;
            float nszz = (szz0[cc] + (sm.x * dvx + sm.z * dvz)) * sm.w;
            float nsxz = (sxz0[cc] + sm.y * ((vxA[id3(dz + 1, dx)] - vxc) + (vzA[id3(dz, dx + 1)] - vzc))) * sm.w;
            if (dz == di && dx == dj) { nsxx += svalA; nszz += svalA; }
            sxxA[k] = nsxx; szzA[k] = nszz; sxzA[k] = nsxz;
        }
        // ---- phase 3: step-B velocities on star r<=1 (5 cells) ----
        float vxB[5], vzB[5];
#pragma unroll
        for (int k = 0; k < 5; ++k) {
            const int dz = D1z[k], dx = D1x[k];
            const int cc = c2 + dz * kP + dx;
            const float2 dd = vmod[cc];
            const float sxxc = sxxA[id2(dz, dx)];
            const float sxzc = sxzA[id2(dz, dx)];
            const float szzc = szzA[id2(dz, dx)];
            vxB[k] = (vxA[id3(dz, dx)] + dd.x * ((sxxA[id2(dz, dx + 1)] - sxxc) + (sxzc - sxzA[id2(dz - 1, dx)]))) * dd.y;
            vzB[k] = (vzA[id3(dz, dx)] + dd.x * ((sxzc - sxzA[id2(dz, dx - 1)]) + (szzA[id2(dz + 1, dx)] - szzc))) * dd.y;
        }
        // ---- phase 4: step-B stress at own cell; store final state ----
        {
            const float4 sm = smod[c2];
            const float dvx = vxB[0] - vxB[2];
            const float dvz = vzB[0] - vzB[4];
            float nsxx = (sxxA[6] + (sm.z * dvx + sm.x * dvz)) * sm.w;
            float nszz = (szzA[6] + (sm.x * dvx + sm.z * dvz)) * sm.w;
            float nsxz = (sxzA[6] + sm.y * ((vxB[3] - vxB[0]) + (vzB[1] - vzB[0]))) * sm.w;
            if (di == 0 && dj == 0) { nsxx += svalB; nszz += svalB; }
            Fn[c2]            = vxB[0];
            Fn[kNC + c2]      = vzB[0];
            Fn[2 * kNC + c2]  = nsxx;
            Fn[3 * kNC + c2]  = nszz;
            Fn[4 * kNC + c2]  = nsxz;
        }
        if (i == kREC_Z && (unsigned)(j - kNPML) < (unsigned)kNX) {
            rsum = vxA[12] * vxA[12] + vxB[0] * vxB[0];   // rec at t and t+1
        }
    }
    // one atomic per wave
    for (int off = 32; off > 0; off >>= 1) rsum += __shfl_down(rsum, off, 64);
    if ((threadIdx.x & 63) == 0 && rsum != 0.0f) atomicAdd(lossp, rsum);
}

__global__ void fwi_finish_kernel(const float* __restrict__ ws,
                                  float* __restrict__ out) {
    out[0] = 0.5f * ws[26 * kNC];
}

extern "C" void kernel_launch(void* const* d_in, const int* in_sizes, int n_in,
                              void* d_out, int out_size, void* d_ws, size_t ws_size,
                              hipStream_t stream) {
    const float* Vp  = (const float*)d_in[0];
    const float* Vs  = (const float*)d_in[1];
    const float* Den = (const float*)d_in[2];
    const float* Stf = (const float*)d_in[3];
    // d_in[4] = Mask (all-ones; identity in forward value) -- unused
    const int* Shot_ids = (const int*)d_in[5];
    float* out = (float*)d_out;
    float* ws  = (float*)d_ws;

    fwi_init_kernel<<<512, 256, 0, stream>>>(Vp, Vs, Den, ws);
    const int blocks = (kNTASK + 255) / 256;  // 1320
    for (int pair = 0; pair < kPAIRS; ++pair) {
        fwi_step2_kernel<<<blocks, 256, 0, stream>>>(ws, Stf, Shot_ids, pair);
    }
    fwi_finish_kernel<<<1, 1, 0, stream>>>(ws, out);
}

// Round 4
// 933.334 us; speedup vs baseline: 1.6117x; 1.6117x over previous
//
#include <hip/hip_runtime.h>
#include <cmath>

namespace {
constexpr int kNZ = 300, kNX = 400;
constexpr int kNPML = 32;
constexpr int kNZP = 364, kNXP = 464;        // padded physical grid
constexpr int kNSTEPS = 200, kNSHOTS = 2;
constexpr int kSRC_Z = 34, kREC_Z = 34;      // NPML + 2
constexpr float kDT = 0.001f;
constexpr float kINV_DX = 100.0f;            // 1/DX

// temporal blocking
constexpr int kT = 4;                         // steps per dispatch
constexpr int kTILE = 48;                     // loaded tile (with halo)
constexpr int kHALO = 2 * kT;                 // 8
constexpr int kINT = kTILE - 2 * kHALO;       // 32 interior
constexpr int kTI = (kNZP + kINT - 1) / kINT; // 12 tile rows
constexpr int kTJ = (kNXP + kINT - 1) / kINT; // 15 tile cols
constexpr int kNTILES = kTI * kTJ;            // 180
constexpr int kBLOCKS = kNTILES * kNSHOTS;    // 360
constexpr int kPAIRS = kNSTEPS / kT;          // 50 dispatches

// guarded global layout: guard 8 top/left, enough bottom/right for overhang
constexpr int kGR = 8 + kNZP + 28;            // 400 rows  (max padded row 391)
constexpr int kGC = 8 + kNXP + 24;            // 496 cols  (max padded col 487)
constexpr int kNG = kGR * kGC;                // 198400
}  // namespace

// ws layout (floats):
//   moduli: [dtr | damp | lam | mu | l2m]  5*kNG  (zero outside physical grid)
//   fields: buf[2][shot][5][kNG]           20*kNG (guard cells stay exactly 0)
//   loss[1]                                @ 25*kNG
// Moduli premultiplied by DT/DX exactly as rounds 2-3 (bit-exact formulas).

__global__ void fwi_init_kernel(const float* __restrict__ Vp,
                                const float* __restrict__ Vs,
                                const float* __restrict__ Den,
                                float* __restrict__ ws) {
    float* dtrA  = ws;
    float* dampA = ws + kNG;
    float* lamA  = ws + 2 * kNG;
    float* muA   = ws + 3 * kNG;
    float* l2mA  = ws + 4 * kNG;
    float* fld   = ws + 5 * kNG;
    float* lossp = ws + 25 * kNG;

    const int gtid = blockIdx.x * blockDim.x + threadIdx.x;
    const int gstride = gridDim.x * blockDim.x;
    for (int g = gtid; g < kNG; g += gstride) {
        const int gr = g / kGC;
        const int gc = g - gr * kGC;
        const int i = gr - 8;            // padded-grid row
        const int j = gc - 8;            // padded-grid col
        float vdtr = 0.0f, vdamp = 0.0f, vlam = 0.0f, vmu = 0.0f, vl2m = 0.0f;
        if (i >= 0 && i < kNZP && j >= 0 && j < kNXP) {
            int iz = i - kNPML; iz = iz < 0 ? 0 : (iz > kNZ - 1 ? kNZ - 1 : iz);
            int jx = j - kNPML; jx = jx < 0 ? 0 : (jx > kNX - 1 ? kNX - 1 : jx);
            const float vp  = Vp[iz * kNX + jx];
            const float vs  = Vs[iz * kNX + jx];
            const float rho = Den[iz * kNX + jx];
            const float m = vs * vs * rho * 1e-6f;
            const float l = (vp * vp - 2.0f * vs * vs) * rho * 1e-6f;
            const float sc = kDT * kINV_DX;
            float dz = fmaxf((float)(kNPML - i), (float)(i - (kNZP - 1 - kNPML)));
            dz = fminf(fmaxf(dz, 0.0f), (float)kNPML) * (1.0f / kNPML);
            float dxx = fmaxf((float)(kNPML - j), (float)(j - (kNXP - 1 - kNPML)));
            dxx = fminf(fmaxf(dxx, 0.0f), (float)kNPML) * (1.0f / kNPML);
            vdamp = expf(-0.1f * (dz * dz + dxx * dxx));
            vdtr  = kDT / rho * kINV_DX;
            vlam  = l * sc;
            vmu   = m * sc;
            vl2m  = (l + 2.0f * m) * sc;
        }
        dtrA[g] = vdtr; dampA[g] = vdamp; lamA[g] = vlam; muA[g] = vmu; l2mA[g] = vl2m;
    }
    for (int c = gtid; c < 20 * kNG; c += gstride) fld[c] = 0.0f;
    if (gtid == 0) lossp[0] = 0.0f;
}

// T=4 timesteps per dispatch. Fields+moduli for each thread's 3x3 patch live
// in registers; LDS carries only the inter-thread edge exchange. Halo cells
// compute garbage after their validity margin expires, but garbage never
// reaches interior cells (L1-radius-1 stencil => margin 2k <= 8), stores, or
// the recorder sum.
__global__ __launch_bounds__(256, 2) void fwi_step_kernel(
    float* __restrict__ ws, const float* __restrict__ Stf,
    const int* __restrict__ Shot_ids, int pair) {
    __shared__ float LBUF[5 * kTILE * kTILE];   // 46 KB
    float* Lvx  = LBUF;
    float* Lvz  = LBUF + kTILE * kTILE;
    float* Lsxx = LBUF + 2 * kTILE * kTILE;
    float* Lszz = LBUF + 3 * kTILE * kTILE;
    float* Lsxz = LBUF + 4 * kTILE * kTILE;

    const float* __restrict__ dtrA  = ws;
    const float* __restrict__ dampA = ws + kNG;
    const float* __restrict__ lamA  = ws + 2 * kNG;
    const float* __restrict__ muA   = ws + 3 * kNG;
    const float* __restrict__ l2mA  = ws + 4 * kNG;
    float* fld   = ws + 5 * kNG;
    float* lossp = ws + 25 * kNG;

    const int b  = blockIdx.x;
    const int s  = b / kNTILES;
    const int tb = b - s * kNTILES;
    const int TI = tb / kTJ;
    const int TJ = tb - TI * kTJ;

    const int tx = threadIdx.x & 15;
    const int ty = threadIdx.x >> 4;
    const int lr0 = 3 * ty;                    // patch rows lr0..lr0+2 in tile
    const int lc0 = 3 * tx;

    const int p = pair & 1;
    const float* Fc = fld + (p * kNSHOTS + s) * 5 * kNG;
    float*       Fn = fld + ((1 - p) * kNSHOTS + s) * 5 * kNG;

    const int id  = Shot_ids[s];
    const int sxp = kNPML + 20 + id * ((kNX - 40) / kNSHOTS);
    float st[kT];
#pragma unroll
    for (int k = 0; k < kT; ++k) st[k] = Stf[id * kNSTEPS + kT * pair + k] * kDT;

    // guarded-array base of this thread's patch (loaded tile origin = TI*32,TJ*32)
    const int gbase = (TI * kINT + lr0) * kGC + TJ * kINT + lc0;
    const int lbase = lr0 * kTILE + lc0;

    // ---- stage: registers + LDS ----
    float vx[3][3], vz[3][3], sxx[3][3], szz[3][3], sxz[3][3];
    float rdtr[3][3], rdamp[3][3], rlam[3][3], rmu[3][3], rl2m[3][3];
    float smf[3][3], recm[3][3];
#pragma unroll
    for (int r = 0; r < 3; ++r) {
#pragma unroll
        for (int c = 0; c < 3; ++c) {
            const int g = gbase + r * kGC + c;
            const int l = lbase + r * kTILE + c;
            vx[r][c]  = Fc[g];
            vz[r][c]  = Fc[kNG + g];
            sxx[r][c] = Fc[2 * kNG + g];
            szz[r][c] = Fc[3 * kNG + g];
            sxz[r][c] = Fc[4 * kNG + g];
            Lvx[l] = vx[r][c]; Lvz[l] = vz[r][c];
            Lsxx[l] = sxx[r][c]; Lszz[l] = szz[r][c]; Lsxz[l] = sxz[r][c];
            rdtr[r][c]  = dtrA[g];
            rdamp[r][c] = dampA[g];
            rlam[r][c]  = lamA[g];
            rmu[r][c]   = muA[g];
            rl2m[r][c]  = l2mA[g];
            const int prow = TI * kINT - kHALO + lr0 + r;
            const int pcol = TJ * kINT - kHALO + lc0 + c;
            smf[r][c]  = (prow == kSRC_Z && pcol == sxp) ? 1.0f : 0.0f;
            const bool inter = (lr0 + r >= kHALO) && (lr0 + r < kHALO + kINT) &&
                               (lc0 + c >= kHALO) && (lc0 + c < kHALO + kINT);
            recm[r][c] = (inter && prow == kREC_Z &&
                          (unsigned)(pcol - kNPML) < (unsigned)kNX) ? 1.0f : 0.0f;
        }
    }
    __syncthreads();

    float rsum = 0.0f;
#pragma unroll
    for (int k = 0; k < kT; ++k) {
        // ---- velocity phase (reads stresses; writes vx,vz) ----
#pragma unroll
        for (int r = 0; r < 3; ++r) {
#pragma unroll
            for (int c = 0; c < 3; ++c) {
                const int l = lbase + r * kTILE + c;
                const float sxxC = sxx[r][c];
                const float sxzC = sxz[r][c];
                const float szzC = szz[r][c];
                const float sxxR = (c < 2) ? sxx[r][c + 1] : Lsxx[l + 1];
                const float sxzU = (r > 0) ? sxz[r - 1][c] : Lsxz[l - kTILE];
                const float sxzL = (c > 0) ? sxz[r][c - 1] : Lsxz[l - 1];
                const float szzD = (r < 2) ? szz[r + 1][c] : Lszz[l + kTILE];
                const float nvx = (vx[r][c] + rdtr[r][c] * ((sxxR - sxxC) + (sxzC - sxzU))) * rdamp[r][c];
                const float nvz = (vz[r][c] + rdtr[r][c] * ((sxzC - sxzL) + (szzD - szzC))) * rdamp[r][c];
                vx[r][c] = nvx;
                vz[r][c] = nvz;
                rsum += recm[r][c] * nvx * nvx;
            }
        }
        // publish velocity edges consumed by neighbors
#pragma unroll
        for (int e = 0; e < 3; ++e) {
            Lvx[lbase + e]                     = vx[0][e];  // top row
            Lvx[lbase + e * kTILE + 2]         = vx[e][2];  // right col
            Lvz[lbase + 2 * kTILE + e]         = vz[2][e];  // bottom row
            Lvz[lbase + e * kTILE]             = vz[e][0];  // left col
        }
        __syncthreads();
        // ---- stress phase (reads velocities; writes stresses; source) ----
#pragma unroll
        for (int r = 0; r < 3; ++r) {
#pragma unroll
            for (int c = 0; c < 3; ++c) {
                const int l = lbase + r * kTILE + c;
                const float vxC = vx[r][c];
                const float vzC = vz[r][c];
                const float vxL = (c > 0) ? vx[r][c - 1] : Lvx[l - 1];
                const float vxD = (r < 2) ? vx[r + 1][c] : Lvx[l + kTILE];
                const float vzU = (r > 0) ? vz[r - 1][c] : Lvz[l - kTILE];
                const float vzR = (c < 2) ? vz[r][c + 1] : Lvz[l + 1];
                const float dvx = vxC - vxL;
                const float dvz = vzC - vzU;
                const float dmp = rdamp[r][c];
                float nsxx = (sxx[r][c] + (rl2m[r][c] * dvx + rlam[r][c] * dvz)) * dmp;
                float nszz = (szz[r][c] + (rlam[r][c] * dvx + rl2m[r][c] * dvz)) * dmp;
                float nsxz = (sxz[r][c] + rmu[r][c] * ((vxD - vxC) + (vzR - vzC))) * dmp;
                const float adds = smf[r][c] * st[k];
                nsxx += adds;
                nszz += adds;
                sxx[r][c] = nsxx;
                szz[r][c] = nszz;
                sxz[r][c] = nsxz;
            }
        }
        // publish stress edges consumed by neighbors
#pragma unroll
        for (int e = 0; e < 3; ++e) {
            Lsxx[lbase + e * kTILE]            = sxx[e][0];  // left col
            Lszz[lbase + e]                    = szz[0][e];  // top row
            Lsxz[lbase + 2 * kTILE + e]        = sxz[2][e];  // bottom row
            Lsxz[lbase + e * kTILE + 2]        = sxz[e][2];  // right col
        }
        __syncthreads();
    }

    // ---- write back interior cells ----
#pragma unroll
    for (int r = 0; r < 3; ++r) {
#pragma unroll
        for (int c = 0; c < 3; ++c) {
            const int lr = lr0 + r, lc = lc0 + c;
            if (lr >= kHALO && lr < kHALO + kINT && lc >= kHALO && lc < kHALO + kINT) {
                const int g = gbase + r * kGC + c;
                Fn[g]            = vx[r][c];
                Fn[kNG + g]      = vz[r][c];
                Fn[2 * kNG + g]  = sxx[r][c];
                Fn[3 * kNG + g]  = szz[r][c];
                Fn[4 * kNG + g]  = sxz[r][c];
            }
        }
    }

    // one atomic per wave for the recorder energy
    for (int off = 32; off > 0; off >>= 1) rsum += __shfl_down(rsum, off, 64);
    if ((threadIdx.x & 63) == 0 && rsum != 0.0f) atomicAdd(lossp, rsum);
}

__global__ void fwi_finish_kernel(const float* __restrict__ ws,
                                  float* __restrict__ out) {
    out[0] = 0.5f * ws[25 * kNG];
}

extern "C" void kernel_launch(void* const* d_in, const int* in_sizes, int n_in,
                              void* d_out, int out_size, void* d_ws, size_t ws_size,
                              hipStream_t stream) {
    const float* Vp  = (const float*)d_in[0];
    const float* Vs  = (const float*)d_in[1];
    const float* Den = (const float*)d_in[2];
    const float* Stf = (const float*)d_in[3];
    // d_in[4] = Mask (all-ones; identity in forward value) -- unused
    const int* Shot_ids = (const int*)d_in[5];
    float* out = (float*)d_out;
    float* ws  = (float*)d_ws;

    fwi_init_kernel<<<512, 256, 0, stream>>>(Vp, Vs, Den, ws);
    for (int pair = 0; pair < kPAIRS; ++pair) {
        fwi_step_kernel<<<kBLOCKS, 256, 0, stream>>>(ws, Stf, Shot_ids, pair);
    }
    fwi_finish_kernel<<<1, 1, 0, stream>>>(ws, out);
}